// Round 1
// baseline (4912.015 us; speedup 1.0000x reference)
//
#include <hip/hip_runtime.h>

// Fused self-attention block, fp32 baseline.
// Shapes: B=8, C=3840, C8=480, N=H*W=1024.
//   q = Wq@x + bq   (B, C8, N)
//   k = Wk@x + bk   (B, C8, N)
//   v = Wv@x + bv   (B, C,  N)
//   E[b,i,j] = sum_o q[b,o,i]*k[b,o,j];  attn = softmax_j(E)
//   out[b,c,i] = gamma * sum_j v[b,c,j]*attn[b,i,j] + x[b,c,i]

namespace {
constexpr int kB  = 8;
constexpr int kC  = 3840;
constexpr int kC8 = 480;
constexpr int kN  = 1024;
}

// ---------------- Kernel 1: combined QKV projection GEMM ----------------
// Combined row space M = 480(q) + 480(k) + 3840(v) = 4800, 75 tiles of 64.
// Out[r][n] = sum_c W(r)[c] * x[b][c][n] + bias(r)
__global__ __launch_bounds__(256)
void proj_qkv(const float* __restrict__ x,
              const float* __restrict__ Wq, const float* __restrict__ bq,
              const float* __restrict__ Wk, const float* __restrict__ bk,
              const float* __restrict__ Wv, const float* __restrict__ bv,
              float* __restrict__ q, float* __restrict__ k, float* __restrict__ v)
{
    __shared__ float a_s[16][68];   // [K][M] transposed weight tile
    __shared__ float b_s[16][68];   // [K][N] x tile

    const int tid = threadIdx.x;
    const int tx = tid & 15, ty = tid >> 4;
    const int n0 = blockIdx.x * 64;
    const int r0 = blockIdx.y * 64;
    const int b  = blockIdx.z;

    // A-tile loader: 64 rows x 16 k, one float4 per thread
    const int ar = tid >> 2;            // 0..63 tile row
    const int ak = (tid & 3) * 4;       // 0,4,8,12
    const int gr = r0 + ar;             // global combined row
    const float* wrow = (gr < kC8)   ? (Wq + (size_t)gr * kC)
                      : (gr < 2*kC8) ? (Wk + (size_t)(gr - kC8) * kC)
                                     : (Wv + (size_t)(gr - 2*kC8) * kC);
    // B-tile loader: 16 k x 64 n, one float4 per thread
    const int bk2 = tid >> 4;           // 0..15
    const int bn  = (tid & 15) * 4;     // 0..60
    const float* xb = x + (size_t)b * kC * kN;

    float acc[4][4] = {};

    for (int k0 = 0; k0 < kC; k0 += 16) {
        float4 av = *(const float4*)(wrow + k0 + ak);
        float4 bw = *(const float4*)(xb + (size_t)(k0 + bk2) * kN + n0 + bn);
        __syncthreads();
        a_s[ak+0][ar] = av.x; a_s[ak+1][ar] = av.y;
        a_s[ak+2][ar] = av.z; a_s[ak+3][ar] = av.w;
        *(float4*)&b_s[bk2][bn] = bw;
        __syncthreads();
#pragma unroll
        for (int kk = 0; kk < 16; ++kk) {
            float4 a4 = *(const float4*)&a_s[kk][ty * 4];
            float4 b4 = *(const float4*)&b_s[kk][tx * 4];
            float aa[4] = {a4.x, a4.y, a4.z, a4.w};
            float bb[4] = {b4.x, b4.y, b4.z, b4.w};
#pragma unroll
            for (int i = 0; i < 4; ++i)
#pragma unroll
                for (int j = 0; j < 4; ++j)
                    acc[i][j] += aa[i] * bb[j];
        }
    }

#pragma unroll
    for (int i = 0; i < 4; ++i) {
        const int r = r0 + ty * 4 + i;
        float bias;
        float* dst;
        if (r < kC8)        { bias = bq[r];         dst = q + ((size_t)b * kC8 + r)          * kN; }
        else if (r < 2*kC8) { bias = bk[r - kC8];   dst = k + ((size_t)b * kC8 + (r - kC8))  * kN; }
        else                { bias = bv[r - 2*kC8]; dst = v + ((size_t)b * kC  + (r - 2*kC8))* kN; }
#pragma unroll
        for (int j = 0; j < 4; ++j)
            dst[n0 + tx * 4 + j] = acc[i][j] + bias;
    }
}

// ---------------- Kernel 2: energy = q^T k ----------------
// E[b][i][j] = sum_o q[b][o][i] * k[b][o][j]
__global__ __launch_bounds__(256)
void energy_gemm(const float* __restrict__ q, const float* __restrict__ k,
                 float* __restrict__ e)
{
    __shared__ float a_s[16][68];   // [o][i]
    __shared__ float b_s[16][68];   // [o][j]

    const int tid = threadIdx.x;
    const int tx = tid & 15, ty = tid >> 4;
    const int j0 = blockIdx.x * 64;
    const int i0 = blockIdx.y * 64;
    const int b  = blockIdx.z;

    const float* qb = q + (size_t)b * kC8 * kN;
    const float* kb = k + (size_t)b * kC8 * kN;

    const int lr = tid >> 4;          // 0..15 (o)
    const int lc = (tid & 15) * 4;    // 0..60

    float acc[4][4] = {};

    for (int o0 = 0; o0 < kC8; o0 += 16) {
        float4 av = *(const float4*)(qb + (size_t)(o0 + lr) * kN + i0 + lc);
        float4 bw = *(const float4*)(kb + (size_t)(o0 + lr) * kN + j0 + lc);
        __syncthreads();
        *(float4*)&a_s[lr][lc] = av;
        *(float4*)&b_s[lr][lc] = bw;
        __syncthreads();
#pragma unroll
        for (int kk = 0; kk < 16; ++kk) {
            float4 a4 = *(const float4*)&a_s[kk][ty * 4];
            float4 b4 = *(const float4*)&b_s[kk][tx * 4];
            float aa[4] = {a4.x, a4.y, a4.z, a4.w};
            float bb[4] = {b4.x, b4.y, b4.z, b4.w};
#pragma unroll
            for (int i = 0; i < 4; ++i)
#pragma unroll
                for (int j = 0; j < 4; ++j)
                    acc[i][j] += aa[i] * bb[j];
        }
    }

    float* eb = e + (size_t)b * kN * kN;
#pragma unroll
    for (int i = 0; i < 4; ++i)
#pragma unroll
        for (int j = 0; j < 4; ++j)
            eb[(size_t)(i0 + ty * 4 + i) * kN + j0 + tx * 4 + j] = acc[i][j];
}

// ---------------- Kernel 3: row softmax in place ----------------
__global__ __launch_bounds__(256)
void softmax_rows(float* __restrict__ attn)
{
    const int i = blockIdx.x;
    const int b = blockIdx.y;
    float* row = attn + ((size_t)b * kN + i) * kN;
    const int tid = threadIdx.x;

    float4 vv = *(const float4*)(row + tid * 4);
    float m = fmaxf(fmaxf(vv.x, vv.y), fmaxf(vv.z, vv.w));

    __shared__ float red[8];
#pragma unroll
    for (int off = 32; off > 0; off >>= 1)
        m = fmaxf(m, __shfl_down(m, off));
    if ((tid & 63) == 0) red[tid >> 6] = m;
    __syncthreads();
    m = fmaxf(fmaxf(red[0], red[1]), fmaxf(red[2], red[3]));

    float e0 = expf(vv.x - m), e1 = expf(vv.y - m);
    float e2 = expf(vv.z - m), e3 = expf(vv.w - m);
    float s = e0 + e1 + e2 + e3;
#pragma unroll
    for (int off = 32; off > 0; off >>= 1)
        s += __shfl_down(s, off);
    if ((tid & 63) == 0) red[4 + (tid >> 6)] = s;
    __syncthreads();
    s = red[4] + red[5] + red[6] + red[7];

    const float inv = 1.0f / s;
    float4 o;
    o.x = e0 * inv; o.y = e1 * inv; o.z = e2 * inv; o.w = e3 * inv;
    *(float4*)(row + tid * 4) = o;
}

// ---------------- Kernel 4: out = gamma * (v @ attn^T) + x ----------------
// out[b][c][n] = gamma * sum_j v[b][c][j]*attn[b][n][j] + x[b][c][n]
__global__ __launch_bounds__(256)
void out_gemm(const float* __restrict__ v, const float* __restrict__ attn,
              const float* __restrict__ x, const float* __restrict__ gamma,
              float* __restrict__ out)
{
    __shared__ float a_s[16][68];   // [j][c]
    __shared__ float b_s[16][68];   // [j][i]

    const int tid = threadIdx.x;
    const int tx = tid & 15, ty = tid >> 4;
    const int n0 = blockIdx.x * 64;
    const int c0 = blockIdx.y * 64;
    const int b  = blockIdx.z;

    const float* vb = v    + (size_t)b * kC * kN;
    const float* ab = attn + (size_t)b * kN * kN;

    const int r  = tid >> 2;          // 0..63
    const int jq = (tid & 3) * 4;     // 0,4,8,12

    float acc[4][4] = {};

    for (int j0 = 0; j0 < kN; j0 += 16) {
        float4 av = *(const float4*)(vb + (size_t)(c0 + r) * kN + j0 + jq);
        float4 bw = *(const float4*)(ab + (size_t)(n0 + r) * kN + j0 + jq);
        __syncthreads();
        a_s[jq+0][r] = av.x; a_s[jq+1][r] = av.y;
        a_s[jq+2][r] = av.z; a_s[jq+3][r] = av.w;
        b_s[jq+0][r] = bw.x; b_s[jq+1][r] = bw.y;
        b_s[jq+2][r] = bw.z; b_s[jq+3][r] = bw.w;
        __syncthreads();
#pragma unroll
        for (int kk = 0; kk < 16; ++kk) {
            float4 a4 = *(const float4*)&a_s[kk][ty * 4];
            float4 b4 = *(const float4*)&b_s[kk][tx * 4];
            float aa[4] = {a4.x, a4.y, a4.z, a4.w};
            float bb[4] = {b4.x, b4.y, b4.z, b4.w};
#pragma unroll
            for (int ci = 0; ci < 4; ++ci)
#pragma unroll
                for (int ii = 0; ii < 4; ++ii)
                    acc[ci][ii] += aa[ci] * bb[ii];
        }
    }

    const float g = gamma[0];
#pragma unroll
    for (int ci = 0; ci < 4; ++ci) {
        const int c = c0 + ty * 4 + ci;
#pragma unroll
        for (int ii = 0; ii < 4; ++ii) {
            const int n = n0 + tx * 4 + ii;
            const size_t idx = ((size_t)b * kC + c) * kN + n;
            out[idx] = g * acc[ci][ii] + x[idx];
        }
    }
}

extern "C" void kernel_launch(void* const* d_in, const int* in_sizes, int n_in,
                              void* d_out, int out_size, void* d_ws, size_t ws_size,
                              hipStream_t stream) {
    const float* x     = (const float*)d_in[0];
    const float* Wq    = (const float*)d_in[1];
    const float* bq    = (const float*)d_in[2];
    const float* Wk    = (const float*)d_in[3];
    const float* bk    = (const float*)d_in[4];
    const float* Wv    = (const float*)d_in[5];
    const float* bv    = (const float*)d_in[6];
    const float* gamma = (const float*)d_in[7];
    float* out = (float*)d_out;

    float* q    = (float*)d_ws;                      // 8*480*1024
    float* k    = q + (size_t)kB * kC8 * kN;         // 8*480*1024
    float* v    = k + (size_t)kB * kC8 * kN;         // 8*3840*1024
    float* attn = v + (size_t)kB * kC  * kN;         // 8*1024*1024

    proj_qkv   <<<dim3(kN/64, 75, kB), 256, 0, stream>>>(x, Wq, bq, Wk, bk, Wv, bv, q, k, v);
    energy_gemm<<<dim3(kN/64, kN/64, kB), 256, 0, stream>>>(q, k, attn);
    softmax_rows<<<dim3(kN, kB), 256, 0, stream>>>(attn);
    out_gemm   <<<dim3(kN/64, kC/64, kB), 256, 0, stream>>>(v, attn, x, gamma, out);
}

// Round 2
// 697.191 us; speedup vs baseline: 7.0454x; 7.0454x over previous
//
#include <hip/hip_runtime.h>
#include <stdint.h>

// Fused self-attention, bf16-MFMA version.
// B=8, C=3840, C8=480, N=1024. All GEMMs as C[m][n] = sum_k A[m][k]*BT[n][k]
// (both operands K-innermost), 128x128 tile, BK=32, mfma_f32_16x16x32_bf16.

typedef __attribute__((ext_vector_type(4))) float f32x4;
typedef __attribute__((ext_vector_type(8))) short bf16x8;
typedef __attribute__((ext_vector_type(4))) short s16x4;

namespace {
constexpr int kB = 8, kC = 3840, kC8 = 480, kN = 1024;
constexpr int kM  = 4800;       // combined rows: q 480 + k 480 + v 3840
constexpr int kMp = 4864;       // padded to 38*128
constexpr int kNT = kB * kN;    // 8192 columns (batch folded)
}

__device__ __forceinline__ short f2bf(float f) {
    union { float f; uint32_t u; } v; v.f = f;
    return (short)((v.u + 0x7FFFu + ((v.u >> 16) & 1u)) >> 16);
}

__device__ __forceinline__ void gl16(const void* g, void* l) {
    __builtin_amdgcn_global_load_lds(
        (const __attribute__((address_space(1))) void*)g,
        (__attribute__((address_space(3))) void*)(uint32_t)(uintptr_t)l,
        16, 0, 0);
}

// ---------------- weight combine + bf16 convert ----------------
__global__ __launch_bounds__(256)
void convert_wc(const float* __restrict__ Wq, const float* __restrict__ Wk,
                const float* __restrict__ Wv, short* __restrict__ Wc)
{
    const size_t g  = (size_t)blockIdx.x * 256 + threadIdx.x;
    const size_t e0 = g * 8;                       // row-major in (4864,3840); 3840%8==0
    const int r = (int)(e0 / kC);
    const int c = (int)(e0 % kC);
    const float* src = nullptr;
    if (r < kC8)          src = Wq + (size_t)r * kC + c;
    else if (r < 2 * kC8) src = Wk + (size_t)(r - kC8) * kC + c;
    else if (r < kM)      src = Wv + (size_t)(r - 2 * kC8) * kC + c;
    bf16x8 o;
    if (src) {
        float4 a = *(const float4*)src;
        float4 b = *(const float4*)(src + 4);
        o[0]=f2bf(a.x); o[1]=f2bf(a.y); o[2]=f2bf(a.z); o[3]=f2bf(a.w);
        o[4]=f2bf(b.x); o[5]=f2bf(b.y); o[6]=f2bf(b.z); o[7]=f2bf(b.w);
    } else {
        o = (bf16x8)0;
    }
    *(bf16x8*)(Wc + e0) = o;
}

__global__ __launch_bounds__(256)
void convert_bias(const float* __restrict__ bq, const float* __restrict__ bk,
                  const float* __restrict__ bv, float* __restrict__ biasC)
{
    const int r = blockIdx.x * 256 + threadIdx.x;
    if (r >= kMp) return;
    biasC[r] = r < kC8 ? bq[r] : r < 2*kC8 ? bk[r - kC8] : r < kM ? bv[r - 2*kC8] : 0.f;
}

// ---------------- x (B,C,N) fp32 -> xbT (B*N, C) bf16 ----------------
__global__ __launch_bounds__(256)
void transpose_x(const float* __restrict__ x, short* __restrict__ xbT)
{
    __shared__ float t[32][33];
    const int tid = threadIdx.x;
    const int b = blockIdx.z, c0 = blockIdx.y * 32, n0 = blockIdx.x * 32;
    const int r = tid >> 3, q4 = (tid & 7) * 4;
    float4 v = *(const float4*)(x + ((size_t)b * kC + c0 + r) * kN + n0 + q4);
    t[r][q4] = v.x; t[r][q4+1] = v.y; t[r][q4+2] = v.z; t[r][q4+3] = v.w;
    __syncthreads();
    s16x4 o;
    o[0] = f2bf(t[q4+0][r]); o[1] = f2bf(t[q4+1][r]);
    o[2] = f2bf(t[q4+2][r]); o[3] = f2bf(t[q4+3][r]);
    *(s16x4*)(xbT + (size_t)(b * kN + n0 + r) * kC + c0 + q4) = o;
}

// ---------------- qkv rows 0..959 -> qT/kT (B*N, 480) bf16 ----------------
__global__ __launch_bounds__(256)
void transpose_qk(const short* __restrict__ qkv, short* __restrict__ qT,
                  short* __restrict__ kT)
{
    __shared__ short t[32][36];
    const int tid = threadIdx.x;
    const int o0 = blockIdx.y * 32, bn0 = blockIdx.x * 32;
    const int r = tid >> 3, q4 = (tid & 7) * 4;
    s16x4 v = *(const s16x4*)(qkv + (size_t)(o0 + r) * kNT + bn0 + q4);
    t[r][q4] = v[0]; t[r][q4+1] = v[1]; t[r][q4+2] = v[2]; t[r][q4+3] = v[3];
    __syncthreads();
    s16x4 o;
    o[0] = t[q4+0][r]; o[1] = t[q4+1][r]; o[2] = t[q4+2][r]; o[3] = t[q4+3][r];
    const int oc = o0 + q4;
    short* dst = (o0 < kC8) ? (qT + (size_t)(bn0 + r) * kC8 + oc)
                            : (kT + (size_t)(bn0 + r) * kC8 + (oc - kC8));
    *(s16x4*)dst = o;
}

// ---------------- unified MFMA GEMM: C = A * B^T ----------------
// A: (M,K) bf16 row-major; B: (N,K) bf16 row-major. 128x128 tile, BK=32.
// MODE 0: proj   -> qkv bf16 (+bias, mask rows>=4800)
// MODE 1: energy -> E fp32
// MODE 2: PV     -> out = gamma*acc + x, fp32
template<int MODE>
__global__ __launch_bounds__(256) void gemm_bt(
    const short* __restrict__ Abase, int lda,
    const short* __restrict__ Bbase, int ldb,
    int ksteps, long zsa, long zsb, long zso,
    short* __restrict__ qkv, const float* __restrict__ biasC,
    float* __restrict__ eout,
    const float* __restrict__ x, const float* __restrict__ gamma,
    float* __restrict__ out)
{
    __shared__ __align__(16) short ldsA[128 * 32];
    __shared__ __align__(16) short ldsB[128 * 32];

    const int tid  = threadIdx.x;
    const int lane = tid & 63;
    const int w    = tid >> 6;
    const int m0 = blockIdx.y * 128;
    const int n0 = blockIdx.x * 128;
    const int z  = blockIdx.z;

    const char* Ab = (const char*)(Abase + (size_t)z * zsa);
    const char* Bb = (const char*)(Bbase + (size_t)z * zsb);
    const size_t ldab = (size_t)lda * 2, ldbb = (size_t)ldb * 2;

    // staging: per wave, 64 lanes x 16B = 1KB contiguous LDS (linear dest).
    const int srow  = w * 16 + (lane >> 2);     // tile row for this lane's 16B
    const int scolb = (lane & 3) * 16;          // byte col within 64B row
    char* lA = (char*)ldsA;
    char* lB = (char*)ldsB;

    f32x4 acc[4][4];
#pragma unroll
    for (int i = 0; i < 4; ++i)
#pragma unroll
        for (int j = 0; j < 4; ++j) acc[i][j] = (f32x4)0.f;

    const int wm = (w >> 1) * 64, wn = (w & 1) * 64;
    const int fr = lane & 15;            // A row / B col within fragment
    const int kb = (lane >> 4) * 16;     // k byte offset (8 bf16 per lane)

    for (int s = 0; s < ksteps; ++s) {
        const int k0b = s * 64;
        if (s) __syncthreads();          // prior reads done before overwrite
        gl16(Ab + (size_t)(m0 + srow)      * ldab + k0b + scolb, lA + w * 1024);
        gl16(Ab + (size_t)(m0 + 64 + srow) * ldab + k0b + scolb, lA + 4096 + w * 1024);
        gl16(Bb + (size_t)(n0 + srow)      * ldbb + k0b + scolb, lB + w * 1024);
        gl16(Bb + (size_t)(n0 + 64 + srow) * ldbb + k0b + scolb, lB + 4096 + w * 1024);
        __syncthreads();                 // vmcnt drain + visibility

        bf16x8 af[4], bfv[4];
#pragma unroll
        for (int f = 0; f < 4; ++f) {
            af[f]  = *(const bf16x8*)(lA + (wm + f * 16 + fr) * 64 + kb);
            bfv[f] = *(const bf16x8*)(lB + (wn + f * 16 + fr) * 64 + kb);
        }
#pragma unroll
        for (int fm = 0; fm < 4; ++fm)
#pragma unroll
            for (int fn = 0; fn < 4; ++fn)
                acc[fm][fn] = __builtin_amdgcn_mfma_f32_16x16x32_bf16(
                    af[fm], bfv[fn], acc[fm][fn], 0, 0, 0);
    }

    // D mapping (m89-verified): col = lane&15, row = (lane>>4)*4 + reg
    const int rbase = (lane >> 4) * 4;
    if (MODE == 0) {
#pragma unroll
        for (int fm = 0; fm < 4; ++fm) {
#pragma unroll
            for (int r = 0; r < 4; ++r) {
                const int gm = m0 + wm + fm * 16 + rbase + r;
                if (gm < kM) {
                    const float bias = biasC[gm];
#pragma unroll
                    for (int fn = 0; fn < 4; ++fn) {
                        const int gn = n0 + wn + fn * 16 + fr;
                        qkv[(size_t)gm * kNT + gn] = f2bf(acc[fm][fn][r] + bias);
                    }
                }
            }
        }
    } else if (MODE == 1) {
        float* eb = eout + (size_t)z * zso;
#pragma unroll
        for (int fm = 0; fm < 4; ++fm)
#pragma unroll
            for (int fn = 0; fn < 4; ++fn)
#pragma unroll
                for (int r = 0; r < 4; ++r)
                    eb[(size_t)(m0 + wm + fm*16 + rbase + r) * kN + (n0 + wn + fn*16 + fr)]
                        = acc[fm][fn][r];
    } else {
        const float g = gamma[0];
        const float* xb = x + (size_t)z * zso;
        float* ob = out + (size_t)z * zso;
#pragma unroll
        for (int fm = 0; fm < 4; ++fm)
#pragma unroll
            for (int fn = 0; fn < 4; ++fn)
#pragma unroll
                for (int r = 0; r < 4; ++r) {
                    const size_t idx = (size_t)(m0 + wm + fm*16 + rbase + r) * kN
                                     + (n0 + wn + fn*16 + fr);
                    ob[idx] = g * acc[fm][fn][r] + xb[idx];
                }
    }
}

// ---------------- row softmax fp32 -> bf16 ----------------
__global__ __launch_bounds__(256)
void softmax_bf(const float* __restrict__ e, short* __restrict__ attnb)
{
    const int i = blockIdx.x, b = blockIdx.y, tid = threadIdx.x;
    const float* row = e + ((size_t)b * kN + i) * kN;

    float4 vv = *(const float4*)(row + tid * 4);
    float m = fmaxf(fmaxf(vv.x, vv.y), fmaxf(vv.z, vv.w));

    __shared__ float red[8];
#pragma unroll
    for (int off = 32; off > 0; off >>= 1)
        m = fmaxf(m, __shfl_down(m, off));
    if ((tid & 63) == 0) red[tid >> 6] = m;
    __syncthreads();
    m = fmaxf(fmaxf(red[0], red[1]), fmaxf(red[2], red[3]));

    float e0 = expf(vv.x - m), e1 = expf(vv.y - m);
    float e2 = expf(vv.z - m), e3 = expf(vv.w - m);
    float s = e0 + e1 + e2 + e3;
#pragma unroll
    for (int off = 32; off > 0; off >>= 1)
        s += __shfl_down(s, off);
    if ((tid & 63) == 0) red[4 + (tid >> 6)] = s;
    __syncthreads();
    s = red[4] + red[5] + red[6] + red[7];

    const float inv = 1.0f / s;
    s16x4 o;
    o[0] = f2bf(e0 * inv); o[1] = f2bf(e1 * inv);
    o[2] = f2bf(e2 * inv); o[3] = f2bf(e3 * inv);
    *(s16x4*)(attnb + ((size_t)b * kN + i) * kN + tid * 4) = o;
}

extern "C" void kernel_launch(void* const* d_in, const int* in_sizes, int n_in,
                              void* d_out, int out_size, void* d_ws, size_t ws_size,
                              hipStream_t stream) {
    const float* x     = (const float*)d_in[0];
    const float* Wq    = (const float*)d_in[1];
    const float* bq    = (const float*)d_in[2];
    const float* Wk    = (const float*)d_in[3];
    const float* bk    = (const float*)d_in[4];
    const float* Wv    = (const float*)d_in[5];
    const float* bv    = (const float*)d_in[6];
    const float* gamma = (const float*)d_in[7];
    float* out = (float*)d_out;

    // ws layout (178.9 MB peak, aliased regions):
    //   [0, 62.9M)        xbT (8192x3840 bf16); after proj reused as:
    //                       attnb @+0 (16.8M), qT @+16.8M (7.9M), kT @+24.6M (7.9M)
    //   [62.9M, 100.3M)   Wc (4864x3840 bf16); after proj reused as attnf (33.6M)
    //   [100.27M, +19K)   biasC (4864 f32)
    //   [100.29M, 178.9M) qkv (4800x8192 bf16)
    char* base = (char*)d_ws;
    short* xbT   = (short*)(base);
    short* attnb = (short*)(base);
    short* qT    = (short*)(base + 16777216);
    short* kT    = (short*)(base + 24641536);
    short* Wc    = (short*)(base + 62914560);
    float* attnf = (float*)(base + 62914560);
    float* biasC = (float*)(base + 100270080);
    short* qkv   = (short*)(base + 100289536);

    convert_wc  <<<9120, 256, 0, stream>>>(Wq, Wk, Wv, Wc);
    convert_bias<<<19, 256, 0, stream>>>(bq, bk, bv, biasC);
    transpose_x <<<dim3(32, 120, 8), 256, 0, stream>>>(x, xbT);

    // proj: (4864 x 3840) * (8192 x 3840)^T -> qkv
    gemm_bt<0><<<dim3(64, 38, 1), 256, 0, stream>>>(
        Wc, kC, xbT, kC, kC / 32, 0, 0, 0,
        qkv, biasC, nullptr, nullptr, nullptr, nullptr);

    transpose_qk<<<dim3(256, 30, 1), 256, 0, stream>>>(qkv, qT, kT);

    // energy: per batch (1024 x 480) * (1024 x 480)^T -> E fp32
    gemm_bt<1><<<dim3(8, 8, 8), 256, 0, stream>>>(
        qT, kC8, kT, kC8, kC8 / 32,
        (long)kN * kC8, (long)kN * kC8, (long)kN * kN,
        nullptr, nullptr, attnf, nullptr, nullptr, nullptr);

    softmax_bf<<<dim3(kN, kB), 256, 0, stream>>>(attnf, attnb);

    // PV: per batch (3840 x 1024) * (1024 x 1024)^T -> out (+x, *gamma)
    gemm_bt<2><<<dim3(8, 30, 8), 256, 0, stream>>>(
        qkv + (size_t)960 * kNT, kNT, attnb, kN, kN / 32,
        (long)kN, (long)kN * kN, (long)kC * kN,
        nullptr, nullptr, nullptr, x, gamma, out);
}

// Round 3
// 572.016 us; speedup vs baseline: 8.5872x; 1.2188x over previous
//
#include <hip/hip_runtime.h>
#include <stdint.h>

// Fused self-attention, bf16-MFMA + pipelined (counted-vmcnt) GEMM.
// B=8, C=3840, C8=480, N=1024. GEMMs: C[m][n] = sum_k A[m][k]*BT[n][k].

typedef __attribute__((ext_vector_type(4))) float f32x4;
typedef __attribute__((ext_vector_type(8))) short bf16x8;
typedef __attribute__((ext_vector_type(4))) short s16x4;

namespace {
constexpr int kB = 8, kC = 3840, kC8 = 480, kN = 1024;
constexpr int kM  = 4800;       // combined rows: q 480 + k 480 + v 3840
constexpr int kMp = 4864;       // padded to 38*128
constexpr int kNT = kB * kN;    // 8192 columns (batch folded)
}

__device__ __forceinline__ short f2bf(float f) {
    union { float f; uint32_t u; } v; v.f = f;
    return (short)((v.u + 0x7FFFu + ((v.u >> 16) & 1u)) >> 16);
}

__device__ __forceinline__ void gl16(const void* g, void* l) {
    __builtin_amdgcn_global_load_lds(
        (const __attribute__((address_space(1))) void*)g,
        (__attribute__((address_space(3))) void*)(uint32_t)(uintptr_t)l,
        16, 0, 0);
}

#define DSR(d, a, o) asm volatile("ds_read_b128 %0, %1 offset:" o \
    : "=v"(d) : "v"(a) : "memory")

// ---------------- weight combine + bf16 convert ----------------
__global__ __launch_bounds__(256)
void convert_wc(const float* __restrict__ Wq, const float* __restrict__ Wk,
                const float* __restrict__ Wv, short* __restrict__ Wc)
{
    const size_t g  = (size_t)blockIdx.x * 256 + threadIdx.x;
    const size_t e0 = g * 8;
    const int r = (int)(e0 / kC);
    const int c = (int)(e0 % kC);
    const float* src = nullptr;
    if (r < kC8)          src = Wq + (size_t)r * kC + c;
    else if (r < 2 * kC8) src = Wk + (size_t)(r - kC8) * kC + c;
    else if (r < kM)      src = Wv + (size_t)(r - 2 * kC8) * kC + c;
    bf16x8 o;
    if (src) {
        float4 a = *(const float4*)src;
        float4 b = *(const float4*)(src + 4);
        o[0]=f2bf(a.x); o[1]=f2bf(a.y); o[2]=f2bf(a.z); o[3]=f2bf(a.w);
        o[4]=f2bf(b.x); o[5]=f2bf(b.y); o[6]=f2bf(b.z); o[7]=f2bf(b.w);
    } else {
        o = (bf16x8)0;
    }
    *(bf16x8*)(Wc + e0) = o;
}

__global__ __launch_bounds__(256)
void convert_bias(const float* __restrict__ bq, const float* __restrict__ bk,
                  const float* __restrict__ bv, float* __restrict__ biasC)
{
    const int r = blockIdx.x * 256 + threadIdx.x;
    if (r >= kMp) return;
    biasC[r] = r < kC8 ? bq[r] : r < 2*kC8 ? bk[r - kC8] : r < kM ? bv[r - 2*kC8] : 0.f;
}

// ---------------- x (B,C,N) fp32 -> xbT (B*N, C) bf16 ----------------
__global__ __launch_bounds__(256)
void transpose_x(const float* __restrict__ x, short* __restrict__ xbT)
{
    __shared__ float t[32][33];
    const int tid = threadIdx.x;
    const int b = blockIdx.z, c0 = blockIdx.y * 32, n0 = blockIdx.x * 32;
    const int r = tid >> 3, q4 = (tid & 7) * 4;
    float4 v = *(const float4*)(x + ((size_t)b * kC + c0 + r) * kN + n0 + q4);
    t[r][q4] = v.x; t[r][q4+1] = v.y; t[r][q4+2] = v.z; t[r][q4+3] = v.w;
    __syncthreads();
    s16x4 o;
    o[0] = f2bf(t[q4+0][r]); o[1] = f2bf(t[q4+1][r]);
    o[2] = f2bf(t[q4+2][r]); o[3] = f2bf(t[q4+3][r]);
    *(s16x4*)(xbT + (size_t)(b * kN + n0 + r) * kC + c0 + q4) = o;
}

// ---------------- qkv rows 0..959 -> qT/kT (B*N, 480) bf16 ----------------
__global__ __launch_bounds__(256)
void transpose_qk(const short* __restrict__ qkv, short* __restrict__ qT,
                  short* __restrict__ kT)
{
    __shared__ short t[32][36];
    const int tid = threadIdx.x;
    const int o0 = blockIdx.y * 32, bn0 = blockIdx.x * 32;
    const int r = tid >> 3, q4 = (tid & 7) * 4;
    s16x4 v = *(const s16x4*)(qkv + (size_t)(o0 + r) * kNT + bn0 + q4);
    t[r][q4] = v[0]; t[r][q4+1] = v[1]; t[r][q4+2] = v[2]; t[r][q4+3] = v[3];
    __syncthreads();
    s16x4 o;
    o[0] = t[q4+0][r]; o[1] = t[q4+1][r]; o[2] = t[q4+2][r]; o[3] = t[q4+3][r];
    const int oc = o0 + q4;
    short* dst = (o0 < kC8) ? (qT + (size_t)(bn0 + r) * kC8 + oc)
                            : (kT + (size_t)(bn0 + r) * kC8 + (oc - kC8));
    *(s16x4*)dst = o;
}

// ---------------- legacy 128x128 MFMA GEMM (energy only) ----------------
__global__ __launch_bounds__(256) void gemm_bt_e(
    const short* __restrict__ Abase, int lda,
    const short* __restrict__ Bbase, int ldb,
    int ksteps, long zsa, long zsb, long zso,
    float* __restrict__ eout)
{
    __shared__ __align__(16) short ldsA[128 * 32];
    __shared__ __align__(16) short ldsB[128 * 32];

    const int tid  = threadIdx.x;
    const int lane = tid & 63;
    const int w    = tid >> 6;
    const int m0 = blockIdx.y * 128;
    const int n0 = blockIdx.x * 128;
    const int z  = blockIdx.z;

    const char* Ab = (const char*)(Abase + (size_t)z * zsa);
    const char* Bb = (const char*)(Bbase + (size_t)z * zsb);
    const size_t ldab = (size_t)lda * 2, ldbb = (size_t)ldb * 2;

    const int srow  = w * 16 + (lane >> 2);
    const int scolb = (lane & 3) * 16;
    char* lA = (char*)ldsA;
    char* lB = (char*)ldsB;

    f32x4 acc[4][4];
#pragma unroll
    for (int i = 0; i < 4; ++i)
#pragma unroll
        for (int j = 0; j < 4; ++j) acc[i][j] = (f32x4)0.f;

    const int wm = (w >> 1) * 64, wn = (w & 1) * 64;
    const int fr = lane & 15;
    const int kb = (lane >> 4) * 16;

    for (int s = 0; s < ksteps; ++s) {
        const int k0b = s * 64;
        if (s) __syncthreads();
        gl16(Ab + (size_t)(m0 + srow)      * ldab + k0b + scolb, lA + w * 1024);
        gl16(Ab + (size_t)(m0 + 64 + srow) * ldab + k0b + scolb, lA + 4096 + w * 1024);
        gl16(Bb + (size_t)(n0 + srow)      * ldbb + k0b + scolb, lB + w * 1024);
        gl16(Bb + (size_t)(n0 + 64 + srow) * ldbb + k0b + scolb, lB + 4096 + w * 1024);
        __syncthreads();

        bf16x8 af[4], bfv[4];
#pragma unroll
        for (int f = 0; f < 4; ++f) {
            af[f]  = *(const bf16x8*)(lA + (wm + f * 16 + fr) * 64 + kb);
            bfv[f] = *(const bf16x8*)(lB + (wn + f * 16 + fr) * 64 + kb);
        }
#pragma unroll
        for (int fm = 0; fm < 4; ++fm)
#pragma unroll
            for (int fn = 0; fn < 4; ++fn)
                acc[fm][fn] = __builtin_amdgcn_mfma_f32_16x16x32_bf16(
                    af[fm], bfv[fn], acc[fm][fn], 0, 0, 0);
    }

    const int rbase = (lane >> 4) * 4;
    float* eb = eout + (size_t)z * zso;
#pragma unroll
    for (int fm = 0; fm < 4; ++fm)
#pragma unroll
        for (int fn = 0; fn < 4; ++fn)
#pragma unroll
            for (int r = 0; r < 4; ++r)
                eb[(size_t)(m0 + wm + fm*16 + rbase + r) * kN + (n0 + wn + fn*16 + fr)]
                    = acc[fm][fn][r];
}

// ---------------- pipelined MFMA GEMM: C = A * B^T ----------------
// Tile 128(M) x 256(N), BK=64, 8 waves (2x4), ring-3 LDS, counted vmcnt,
// raw barriers, XOR-swizzled LDS (both-sides), setprio around MFMA.
// MODE 0: proj -> qkv bf16 (+bias). MODE 2: PV -> out = gamma*acc + x.
template<int MODE>
__global__ __launch_bounds__(512) void gemm8(
    const short* __restrict__ Abase, int lda,
    const short* __restrict__ Bbase, int ldb,
    int ksteps, long zsa, long zsb, long zso,
    short* __restrict__ qkv, const float* __restrict__ biasC,
    const float* __restrict__ x, const float* __restrict__ gamma,
    float* __restrict__ out)
{
    // 3 slots x (A 16KB + B 32KB) = 144 KB
    __shared__ __align__(16) char lds[147456];

    const int tid  = threadIdx.x;
    const int lane = tid & 63;
    const int w    = tid >> 6;

    // bijective XCD swizzle over the full grid (m204)
    const int gx = gridDim.x, gy = gridDim.y;
    const int nwg = gx * gy * gridDim.z;
    const int id = ((int)blockIdx.z * gy + (int)blockIdx.y) * gx + (int)blockIdx.x;
    const int qd = nwg >> 3, rd = nwg & 7;
    const int xcd = id & 7, pos = id >> 3;
    const int sw = (xcd < rd ? xcd * (qd + 1) : rd * (qd + 1) + (xcd - rd) * qd) + pos;
    const int bz = sw / (gx * gy);
    const int rem = sw % (gx * gy);
    const int m0 = (rem / gx) * 128;
    const int n0 = (rem % gx) * 256;

    const char* Ab = (const char*)(Abase + (size_t)bz * zsa);
    const char* Bb = (const char*)(Bbase + (size_t)bz * zsb);
    const size_t ldab = (size_t)lda * 2, ldbb = (size_t)ldb * 2;

    // ---- staging geometry (pre-swizzled global source, linear LDS dest) ----
    const int r8  = tid >> 3;                                   // 0..63
    const int scb = ((tid & 7) * 16) ^ ((r8 & 7) << 4);         // swizzled col byte
    char* const ldsAp = lds;            // +slot*49152
    char* const ldsBp = lds + 16384;

#define STAGE(S, SLOTBASE)                                                     \
    do {                                                                       \
        const size_t kb_ = (size_t)(S) * 128;                                  \
        _Pragma("unroll")                                                      \
        for (int i_ = 0; i_ < 2; ++i_)                                         \
            gl16(Ab + (size_t)(m0 + r8 + 64 * i_) * ldab + kb_ + scb,          \
                 (SLOTBASE) + i_ * 8192 + w * 1024);                           \
        _Pragma("unroll")                                                      \
        for (int i_ = 0; i_ < 4; ++i_)                                         \
            gl16(Bb + (size_t)(n0 + r8 + 64 * i_) * ldbb + kb_ + scb,          \
                 (SLOTBASE) + 16384 + i_ * 8192 + w * 1024);                   \
    } while (0)

    // ---- fragment-read addresses (uint32 LDS offsets) ----
    const uint32_t lbase = (uint32_t)(uintptr_t)&lds[0];
    const int wr = w >> 2, wc = w & 3;
    const int fr = lane & 15, kq = lane >> 4;
    const uint32_t xorv = (uint32_t)((fr & 7) << 4);
    const uint32_t aoff0 = (uint32_t)((wr * 64 + fr) * 128) + (((uint32_t)(kq * 16)) ^ xorv);
    const uint32_t aoff1 = (uint32_t)((wr * 64 + fr) * 128) + (((uint32_t)(64 + kq * 16)) ^ xorv);
    const uint32_t boff0 = 16384u + (uint32_t)((wc * 64 + fr) * 128) + (((uint32_t)(kq * 16)) ^ xorv);
    const uint32_t boff1 = 16384u + (uint32_t)((wc * 64 + fr) * 128) + (((uint32_t)(64 + kq * 16)) ^ xorv);

    f32x4 acc[4][4];
#pragma unroll
    for (int i = 0; i < 4; ++i)
#pragma unroll
        for (int j = 0; j < 4; ++j) acc[i][j] = (f32x4)0.f;

    // ---- prologue: stage steps 0,1,2 (18 gl16 in flight) ----
    const int npro = ksteps < 3 ? ksteps : 3;
    for (int p = 0; p < npro; ++p)
        STAGE(p, lds + p * 49152);

    int slot = 0;
    for (int s = 0; s < ksteps; ++s) {
        // B1: step-s data landed (leave steps s+1,s+2 = 12 loads in flight)
        if (s + 2 < ksteps)      asm volatile("s_waitcnt vmcnt(12)" ::: "memory");
        else if (s + 1 < ksteps) asm volatile("s_waitcnt vmcnt(6)" ::: "memory");
        else                     asm volatile("s_waitcnt vmcnt(0)" ::: "memory");
        __builtin_amdgcn_s_barrier();

        const uint32_t sb = lbase + (uint32_t)slot * 49152u;
        const uint32_t aa0 = sb + aoff0, aa1 = sb + aoff1;
        const uint32_t bb0 = sb + boff0, bb1 = sb + boff1;

        bf16x8 a0[4], a1[4], b0v[4], b1v[4];
        // R0: k-substep 0 (8 reads)
        DSR(a0[0], aa0, "0"); DSR(a0[1], aa0, "2048");
        DSR(a0[2], aa0, "4096"); DSR(a0[3], aa0, "6144");
        DSR(b0v[0], bb0, "0"); DSR(b0v[1], bb0, "2048");
        DSR(b0v[2], bb0, "4096"); DSR(b0v[3], bb0, "6144");
        // R1: k-substep 1 (8 reads)
        DSR(a1[0], aa1, "0"); DSR(a1[1], aa1, "2048");
        DSR(a1[2], aa1, "4096"); DSR(a1[3], aa1, "6144");
        DSR(b1v[0], bb1, "0"); DSR(b1v[1], bb1, "2048");
        DSR(b1v[2], bb1, "4096"); DSR(b1v[3], bb1, "6144");

        asm volatile("s_waitcnt lgkmcnt(8)" ::: "memory");   // R0 complete
        __builtin_amdgcn_sched_barrier(0);
        __builtin_amdgcn_s_setprio(1);
#pragma unroll
        for (int fm = 0; fm < 4; ++fm)
#pragma unroll
            for (int fn = 0; fn < 4; ++fn)
                acc[fm][fn] = __builtin_amdgcn_mfma_f32_16x16x32_bf16(
                    a0[fm], b0v[fn], acc[fm][fn], 0, 0, 0);
        __builtin_amdgcn_s_setprio(0);

        asm volatile("s_waitcnt lgkmcnt(0)" ::: "memory");   // R1 complete
        __builtin_amdgcn_sched_barrier(0);
        __builtin_amdgcn_s_barrier();      // B2: all waves done reading slot

        if (s + 3 < ksteps)
            STAGE(s + 3, lds + slot * 49152);   // (s+3)%3 == slot
        __builtin_amdgcn_sched_barrier(0);

        __builtin_amdgcn_s_setprio(1);
#pragma unroll
        for (int fm = 0; fm < 4; ++fm)
#pragma unroll
            for (int fn = 0; fn < 4; ++fn)
                acc[fm][fn] = __builtin_amdgcn_mfma_f32_16x16x32_bf16(
                    a1[fm], b1v[fn], acc[fm][fn], 0, 0, 0);
        __builtin_amdgcn_s_setprio(0);

        slot = (slot == 2) ? 0 : slot + 1;
    }
#undef STAGE

    // ---- epilogue: D mapping col = lane&15, row = (lane>>4)*4 + reg ----
    const int rbase = kq * 4;
    if (MODE == 0) {
#pragma unroll
        for (int fm = 0; fm < 4; ++fm) {
#pragma unroll
            for (int rr = 0; rr < 4; ++rr) {
                const int gm = m0 + wr * 64 + fm * 16 + rbase + rr;
                if (gm < kM) {
                    const float bias = biasC[gm];
#pragma unroll
                    for (int fn = 0; fn < 4; ++fn) {
                        const int gn = n0 + wc * 64 + fn * 16 + fr;
                        qkv[(size_t)gm * kNT + gn] = f2bf(acc[fm][fn][rr] + bias);
                    }
                }
            }
        }
    } else {
        const float g = gamma[0];
        const float* xb = x + (size_t)bz * zso;
        float* ob = out + (size_t)bz * zso;
#pragma unroll
        for (int fm = 0; fm < 4; ++fm)
#pragma unroll
            for (int fn = 0; fn < 4; ++fn)
#pragma unroll
                for (int rr = 0; rr < 4; ++rr) {
                    const size_t idx = (size_t)(m0 + wr*64 + fm*16 + rbase + rr) * kN
                                     + (n0 + wc*64 + fn*16 + fr);
                    ob[idx] = g * acc[fm][fn][rr] + xb[idx];
                }
    }
}

// ---------------- row softmax fp32 -> bf16 ----------------
__global__ __launch_bounds__(256)
void softmax_bf(const float* __restrict__ e, short* __restrict__ attnb)
{
    const int i = blockIdx.x, b = blockIdx.y, tid = threadIdx.x;
    const float* row = e + ((size_t)b * kN + i) * kN;

    float4 vv = *(const float4*)(row + tid * 4);
    float m = fmaxf(fmaxf(vv.x, vv.y), fmaxf(vv.z, vv.w));

    __shared__ float red[8];
#pragma unroll
    for (int off = 32; off > 0; off >>= 1)
        m = fmaxf(m, __shfl_down(m, off));
    if ((tid & 63) == 0) red[tid >> 6] = m;
    __syncthreads();
    m = fmaxf(fmaxf(red[0], red[1]), fmaxf(red[2], red[3]));

    float e0 = expf(vv.x - m), e1 = expf(vv.y - m);
    float e2 = expf(vv.z - m), e3 = expf(vv.w - m);
    float s = e0 + e1 + e2 + e3;
#pragma unroll
    for (int off = 32; off > 0; off >>= 1)
        s += __shfl_down(s, off);
    if ((tid & 63) == 0) red[4 + (tid >> 6)] = s;
    __syncthreads();
    s = red[4] + red[5] + red[6] + red[7];

    const float inv = 1.0f / s;
    s16x4 o;
    o[0] = f2bf(e0 * inv); o[1] = f2bf(e1 * inv);
    o[2] = f2bf(e2 * inv); o[3] = f2bf(e3 * inv);
    *(s16x4*)(attnb + ((size_t)b * kN + i) * kN + tid * 4) = o;
}

extern "C" void kernel_launch(void* const* d_in, const int* in_sizes, int n_in,
                              void* d_out, int out_size, void* d_ws, size_t ws_size,
                              hipStream_t stream) {
    const float* x     = (const float*)d_in[0];
    const float* Wq    = (const float*)d_in[1];
    const float* bq    = (const float*)d_in[2];
    const float* Wk    = (const float*)d_in[3];
    const float* bk    = (const float*)d_in[4];
    const float* Wv    = (const float*)d_in[5];
    const float* bv    = (const float*)d_in[6];
    const float* gamma = (const float*)d_in[7];
    float* out = (float*)d_out;

    char* base = (char*)d_ws;
    short* xbT   = (short*)(base);
    short* attnb = (short*)(base);
    short* qT    = (short*)(base + 16777216);
    short* kT    = (short*)(base + 24641536);
    short* Wc    = (short*)(base + 62914560);
    float* attnf = (float*)(base + 62914560);
    float* biasC = (float*)(base + 100270080);
    short* qkv   = (short*)(base + 100289536);

    convert_wc  <<<9120, 256, 0, stream>>>(Wq, Wk, Wv, Wc);
    convert_bias<<<19, 256, 0, stream>>>(bq, bk, bv, biasC);
    transpose_x <<<dim3(32, 120, 8), 256, 0, stream>>>(x, xbT);

    // proj: (4864 x 3840) * (8192 x 3840)^T -> qkv   [pipelined]
    gemm8<0><<<dim3(32, 38, 1), 512, 0, stream>>>(
        Wc, kC, xbT, kC, kC / 64, 0, 0, 0,
        qkv, biasC, nullptr, nullptr, nullptr);

    transpose_qk<<<dim3(256, 30, 1), 256, 0, stream>>>(qkv, qT, kT);

    // energy: per batch (1024 x 480) * (1024 x 480)^T -> E fp32  [legacy]
    gemm_bt_e<<<dim3(8, 8, 8), 256, 0, stream>>>(
        qT, kC8, kT, kC8, kC8 / 32,
        (long)kN * kC8, (long)kN * kC8, (long)kN * kN, attnf);

    softmax_bf<<<dim3(kN, kB), 256, 0, stream>>>(attnf, attnb);

    // PV: per batch (3840 x 1024) * (1024 x 1024)^T -> out  [pipelined]
    gemm8<2><<<dim3(4, 30, 8), 512, 0, stream>>>(
        qkv + (size_t)960 * kNT, kNT, attnb, kN, kN / 64,
        (long)kN, (long)kN * kN, (long)kC * kN,
        nullptr, nullptr, x, gamma, out);
}

// Round 4
// 514.605 us; speedup vs baseline: 9.5452x; 1.1116x over previous
//
#include <hip/hip_runtime.h>
#include <stdint.h>

// Fused self-attention, bf16-MFMA. 256x256-tile pipelined GEMM (ring-2 LDS,
// counted vmcnt, XOR-swizzled), m-fastest tile order for L3 reuse.
// B=8, C=3840, C8=480, N=1024. GEMMs: C[m][n] = sum_k A[m][k]*BT[n][k].

typedef __attribute__((ext_vector_type(4))) float f32x4;
typedef __attribute__((ext_vector_type(8))) short bf16x8;
typedef __attribute__((ext_vector_type(4))) short s16x4;

namespace {
constexpr int kB = 8, kC = 3840, kC8 = 480, kN = 1024;
constexpr int kM  = 4800;       // combined rows: q 480 + k 480 + v 3840
constexpr int kMp = 4864;       // padded to 19*256
constexpr int kNT = kB * kN;    // 8192 columns (batch folded)
}

__device__ __forceinline__ short f2bf(float f) {
    union { float f; uint32_t u; } v; v.f = f;
    return (short)((v.u + 0x7FFFu + ((v.u >> 16) & 1u)) >> 16);
}

__device__ __forceinline__ void gl16(const void* g, void* l) {
    __builtin_amdgcn_global_load_lds(
        (const __attribute__((address_space(1))) void*)g,
        (__attribute__((address_space(3))) void*)(uint32_t)(uintptr_t)l,
        16, 0, 0);
}

#define DSR(d, a, o) asm volatile("ds_read_b128 %0, %1 offset:" o \
    : "=v"(d) : "v"(a) : "memory")

// ---------------- weight combine + bf16 convert ----------------
__global__ __launch_bounds__(256)
void convert_wc(const float* __restrict__ Wq, const float* __restrict__ Wk,
                const float* __restrict__ Wv, short* __restrict__ Wc)
{
    const size_t g  = (size_t)blockIdx.x * 256 + threadIdx.x;
    const size_t e0 = g * 8;
    const int r = (int)(e0 / kC);
    const int c = (int)(e0 % kC);
    const float* src = nullptr;
    if (r < kC8)          src = Wq + (size_t)r * kC + c;
    else if (r < 2 * kC8) src = Wk + (size_t)(r - kC8) * kC + c;
    else if (r < kM)      src = Wv + (size_t)(r - 2 * kC8) * kC + c;
    bf16x8 o;
    if (src) {
        float4 a = *(const float4*)src;
        float4 b = *(const float4*)(src + 4);
        o[0]=f2bf(a.x); o[1]=f2bf(a.y); o[2]=f2bf(a.z); o[3]=f2bf(a.w);
        o[4]=f2bf(b.x); o[5]=f2bf(b.y); o[6]=f2bf(b.z); o[7]=f2bf(b.w);
    } else {
        o = (bf16x8)0;
    }
    *(bf16x8*)(Wc + e0) = o;
}

__global__ __launch_bounds__(256)
void convert_bias(const float* __restrict__ bq, const float* __restrict__ bk,
                  const float* __restrict__ bv, float* __restrict__ biasC)
{
    const int r = blockIdx.x * 256 + threadIdx.x;
    if (r >= kMp) return;
    biasC[r] = r < kC8 ? bq[r] : r < 2*kC8 ? bk[r - kC8] : r < kM ? bv[r - 2*kC8] : 0.f;
}

// ---------------- x (B,C,N) fp32 -> xbT (B*N, C) bf16 ----------------
__global__ __launch_bounds__(256)
void transpose_x(const float* __restrict__ x, short* __restrict__ xbT)
{
    __shared__ float t[32][33];
    const int tid = threadIdx.x;
    const int b = blockIdx.z, c0 = blockIdx.y * 32, n0 = blockIdx.x * 32;
    const int r = tid >> 3, q4 = (tid & 7) * 4;
    float4 v = *(const float4*)(x + ((size_t)b * kC + c0 + r) * kN + n0 + q4);
    t[r][q4] = v.x; t[r][q4+1] = v.y; t[r][q4+2] = v.z; t[r][q4+3] = v.w;
    __syncthreads();
    s16x4 o;
    o[0] = f2bf(t[q4+0][r]); o[1] = f2bf(t[q4+1][r]);
    o[2] = f2bf(t[q4+2][r]); o[3] = f2bf(t[q4+3][r]);
    *(s16x4*)(xbT + (size_t)(b * kN + n0 + r) * kC + c0 + q4) = o;
}

// ---------------- qkv rows 0..959 -> qT/kT (B*N, 480) bf16 ----------------
__global__ __launch_bounds__(256)
void transpose_qk(const short* __restrict__ qkv, short* __restrict__ qT,
                  short* __restrict__ kT)
{
    __shared__ short t[32][36];
    const int tid = threadIdx.x;
    const int o0 = blockIdx.y * 32, bn0 = blockIdx.x * 32;
    const int r = tid >> 3, q4 = (tid & 7) * 4;
    s16x4 v = *(const s16x4*)(qkv + (size_t)(o0 + r) * kNT + bn0 + q4);
    t[r][q4] = v[0]; t[r][q4+1] = v[1]; t[r][q4+2] = v[2]; t[r][q4+3] = v[3];
    __syncthreads();
    s16x4 o;
    o[0] = t[q4+0][r]; o[1] = t[q4+1][r]; o[2] = t[q4+2][r]; o[3] = t[q4+3][r];
    const int oc = o0 + q4;
    short* dst = (o0 < kC8) ? (qT + (size_t)(bn0 + r) * kC8 + oc)
                            : (kT + (size_t)(bn0 + r) * kC8 + (oc - kC8));
    *(s16x4*)dst = o;
}

// ---------------- legacy 128x128 MFMA GEMM (energy only) ----------------
__global__ __launch_bounds__(256) void gemm_bt_e(
    const short* __restrict__ Abase, int lda,
    const short* __restrict__ Bbase, int ldb,
    int ksteps, long zsa, long zsb, long zso,
    float* __restrict__ eout)
{
    __shared__ __align__(16) short ldsA[128 * 32];
    __shared__ __align__(16) short ldsB[128 * 32];

    const int tid  = threadIdx.x;
    const int lane = tid & 63;
    const int w    = tid >> 6;
    const int m0 = blockIdx.y * 128;
    const int n0 = blockIdx.x * 128;
    const int z  = blockIdx.z;

    const char* Ab = (const char*)(Abase + (size_t)z * zsa);
    const char* Bb = (const char*)(Bbase + (size_t)z * zsb);
    const size_t ldab = (size_t)lda * 2, ldbb = (size_t)ldb * 2;

    const int srow  = w * 16 + (lane >> 2);
    const int scolb = (lane & 3) * 16;
    char* lA = (char*)ldsA;
    char* lB = (char*)ldsB;

    f32x4 acc[4][4];
#pragma unroll
    for (int i = 0; i < 4; ++i)
#pragma unroll
        for (int j = 0; j < 4; ++j) acc[i][j] = (f32x4)0.f;

    const int wm = (w >> 1) * 64, wn = (w & 1) * 64;
    const int fr = lane & 15;
    const int kb = (lane >> 4) * 16;

    for (int s = 0; s < ksteps; ++s) {
        const int k0b = s * 64;
        if (s) __syncthreads();
        gl16(Ab + (size_t)(m0 + srow)      * ldab + k0b + scolb, lA + w * 1024);
        gl16(Ab + (size_t)(m0 + 64 + srow) * ldab + k0b + scolb, lA + 4096 + w * 1024);
        gl16(Bb + (size_t)(n0 + srow)      * ldbb + k0b + scolb, lB + w * 1024);
        gl16(Bb + (size_t)(n0 + 64 + srow) * ldbb + k0b + scolb, lB + 4096 + w * 1024);
        __syncthreads();

        bf16x8 af[4], bfv[4];
#pragma unroll
        for (int f = 0; f < 4; ++f) {
            af[f]  = *(const bf16x8*)(lA + (wm + f * 16 + fr) * 64 + kb);
            bfv[f] = *(const bf16x8*)(lB + (wn + f * 16 + fr) * 64 + kb);
        }
#pragma unroll
        for (int fm = 0; fm < 4; ++fm)
#pragma unroll
            for (int fn = 0; fn < 4; ++fn)
                acc[fm][fn] = __builtin_amdgcn_mfma_f32_16x16x32_bf16(
                    af[fm], bfv[fn], acc[fm][fn], 0, 0, 0);
    }

    const int rbase = (lane >> 4) * 4;
    float* eb = eout + (size_t)z * zso;
#pragma unroll
    for (int fm = 0; fm < 4; ++fm)
#pragma unroll
        for (int fn = 0; fn < 4; ++fn)
#pragma unroll
            for (int r = 0; r < 4; ++r)
                eb[(size_t)(m0 + wm + fm*16 + rbase + r) * kN + (n0 + wn + fn*16 + fr)]
                    = acc[fm][fn][r];
}

// ---------------- 256x256 pipelined MFMA GEMM: C = A * B^T ----------------
// BK=64, 512 threads (8 waves, 2x4), per-wave 128x64 output, ring-2 LDS
// (2 x 64KB), counted vmcnt(8), XOR-swizzled LDS, grouped ds_read||MFMA.
// Grid: x = M-tiles (fastest, for L3 reuse of A), y = N-tiles, z = batch.
// MODE 0: proj -> qkv bf16 (+bias, mask rows >= 4800).
// MODE 2: PV   -> out = gamma*acc + x (fp32).
template<int MODE>
__global__ __launch_bounds__(512) void gemm256(
    const short* __restrict__ Abase, int lda,
    const short* __restrict__ Bbase, int ldb,
    int ksteps, long zsa, long zsb, long zso,
    short* __restrict__ qkv, const float* __restrict__ biasC,
    const float* __restrict__ x, const float* __restrict__ gamma,
    float* __restrict__ out)
{
    // 2 slots x (A 32KB + B 32KB) = 128 KB
    __shared__ __align__(16) char lds[131072];

    const int tid  = threadIdx.x;
    const int lane = tid & 63;
    const int w    = tid >> 6;

    const int m0 = blockIdx.x * 256;
    const int n0 = blockIdx.y * 256;
    const int bz = blockIdx.z;

    const char* Ab = (const char*)(Abase + (size_t)bz * zsa);
    const char* Bb = (const char*)(Bbase + (size_t)bz * zsb);
    const size_t ldab = (size_t)lda * 2, ldbb = (size_t)ldb * 2;

    // ---- staging geometry (pre-swizzled global source, linear LDS dest) ----
    const int r8  = tid >> 3;                                   // 0..63
    const int scb = ((tid & 7) * 16) ^ ((r8 & 7) << 4);         // swizzled col byte

#define STAGE(S, SLOTBASE)                                                     \
    do {                                                                       \
        const size_t kb_ = (size_t)(S) * 128;                                  \
        _Pragma("unroll")                                                      \
        for (int i_ = 0; i_ < 4; ++i_)                                         \
            gl16(Ab + (size_t)(m0 + r8 + 64 * i_) * ldab + kb_ + scb,          \
                 (SLOTBASE) + i_ * 8192 + w * 1024);                           \
        _Pragma("unroll")                                                      \
        for (int i_ = 0; i_ < 4; ++i_)                                         \
            gl16(Bb + (size_t)(n0 + r8 + 64 * i_) * ldbb + kb_ + scb,          \
                 (SLOTBASE) + 32768 + i_ * 8192 + w * 1024);                   \
    } while (0)

    // ---- fragment-read addresses (uint32 LDS offsets) ----
    const uint32_t lbase = (uint32_t)(uintptr_t)&lds[0];
    const int wr = w >> 2, wc = w & 3;          // wave tile: 128 rows x 64 cols
    const int fr = lane & 15, kq = lane >> 4;
    const uint32_t xorv = (uint32_t)((fr & 7) << 4);
    const uint32_t aoff0 = (uint32_t)((wr*128 + fr) * 128) + (((uint32_t)(kq*16)) ^ xorv);
    const uint32_t aoff1 = (uint32_t)((wr*128 + fr) * 128) + (((uint32_t)(64 + kq*16)) ^ xorv);
    const uint32_t boff0 = 32768u + (uint32_t)((wc*64 + fr) * 128) + (((uint32_t)(kq*16)) ^ xorv);
    const uint32_t boff1 = 32768u + (uint32_t)((wc*64 + fr) * 128) + (((uint32_t)(64 + kq*16)) ^ xorv);

    f32x4 acc[8][4];
#pragma unroll
    for (int i = 0; i < 8; ++i)
#pragma unroll
        for (int j = 0; j < 4; ++j) acc[i][j] = (f32x4)0.f;

    // ---- prologue: stage tiles 0,1 (16 gl16 in flight) ----
    STAGE(0, lds);
    STAGE(1, lds + 65536);

    const int ns = ksteps;
    for (int s = 0; s < ns; ++s) {
        const uint32_t cur = (uint32_t)(s & 1);
        // tile-s loads landed; tile s+1's 8 stay in flight
        if (s + 1 < ns) asm volatile("s_waitcnt vmcnt(8)" ::: "memory");
        else            asm volatile("s_waitcnt vmcnt(0)" ::: "memory");
        __builtin_amdgcn_sched_barrier(0);
        __builtin_amdgcn_s_barrier();
        __builtin_amdgcn_sched_barrier(0);

        const uint32_t sb = lbase + cur * 65536u;
        const uint32_t aa0 = sb + aoff0, aa1 = sb + aoff1;
        const uint32_t bb0 = sb + boff0, bb1 = sb + boff1;

        bf16x8 b0v[4], b1v[4], a0[8], a1[8];
        // B all (8 reads)
        DSR(b0v[0], bb0, "0");    DSR(b0v[1], bb0, "2048");
        DSR(b0v[2], bb0, "4096"); DSR(b0v[3], bb0, "6144");
        DSR(b1v[0], bb1, "0");    DSR(b1v[1], bb1, "2048");
        DSR(b1v[2], bb1, "4096"); DSR(b1v[3], bb1, "6144");
        // A m0,m1 then m2,m3 (8 reads)
        DSR(a0[0], aa0, "0");    DSR(a0[1], aa0, "2048");
        DSR(a1[0], aa1, "0");    DSR(a1[1], aa1, "2048");
        DSR(a0[2], aa0, "4096"); DSR(a0[3], aa0, "6144");
        DSR(a1[2], aa1, "4096"); DSR(a1[3], aa1, "6144");

        asm volatile("s_waitcnt lgkmcnt(4)" ::: "memory");   // B + m0,m1 done
        __builtin_amdgcn_sched_barrier(0);
        __builtin_amdgcn_s_setprio(1);
#pragma unroll
        for (int fm = 0; fm < 2; ++fm)
#pragma unroll
            for (int fn = 0; fn < 4; ++fn) {
                acc[fm][fn] = __builtin_amdgcn_mfma_f32_16x16x32_bf16(a0[fm], b0v[fn], acc[fm][fn], 0, 0, 0);
                acc[fm][fn] = __builtin_amdgcn_mfma_f32_16x16x32_bf16(a1[fm], b1v[fn], acc[fm][fn], 0, 0, 0);
            }
        __builtin_amdgcn_s_setprio(0);

        DSR(a0[4], aa0, "8192"); DSR(a0[5], aa0, "10240");
        DSR(a1[4], aa1, "8192"); DSR(a1[5], aa1, "10240");
        asm volatile("s_waitcnt lgkmcnt(4)" ::: "memory");   // m2,m3 done
        __builtin_amdgcn_sched_barrier(0);
        __builtin_amdgcn_s_setprio(1);
#pragma unroll
        for (int fm = 2; fm < 4; ++fm)
#pragma unroll
            for (int fn = 0; fn < 4; ++fn) {
                acc[fm][fn] = __builtin_amdgcn_mfma_f32_16x16x32_bf16(a0[fm], b0v[fn], acc[fm][fn], 0, 0, 0);
                acc[fm][fn] = __builtin_amdgcn_mfma_f32_16x16x32_bf16(a1[fm], b1v[fn], acc[fm][fn], 0, 0, 0);
            }
        __builtin_amdgcn_s_setprio(0);

        DSR(a0[6], aa0, "12288"); DSR(a0[7], aa0, "14336");
        DSR(a1[6], aa1, "12288"); DSR(a1[7], aa1, "14336");
        asm volatile("s_waitcnt lgkmcnt(4)" ::: "memory");   // m4,m5 done
        __builtin_amdgcn_sched_barrier(0);
        __builtin_amdgcn_s_setprio(1);
#pragma unroll
        for (int fm = 4; fm < 6; ++fm)
#pragma unroll
            for (int fn = 0; fn < 4; ++fn) {
                acc[fm][fn] = __builtin_amdgcn_mfma_f32_16x16x32_bf16(a0[fm], b0v[fn], acc[fm][fn], 0, 0, 0);
                acc[fm][fn] = __builtin_amdgcn_mfma_f32_16x16x32_bf16(a1[fm], b1v[fn], acc[fm][fn], 0, 0, 0);
            }
        __builtin_amdgcn_s_setprio(0);

        asm volatile("s_waitcnt lgkmcnt(0)" ::: "memory");   // m6,m7 done
        __builtin_amdgcn_sched_barrier(0);
        __builtin_amdgcn_s_barrier();      // all waves done reading slot cur
        __builtin_amdgcn_sched_barrier(0);

        if (s + 2 < ns)
            STAGE(s + 2, lds + cur * 65536);   // overwrite consumed slot
        __builtin_amdgcn_sched_barrier(0);

        __builtin_amdgcn_s_setprio(1);
#pragma unroll
        for (int fm = 6; fm < 8; ++fm)
#pragma unroll
            for (int fn = 0; fn < 4; ++fn) {
                acc[fm][fn] = __builtin_amdgcn_mfma_f32_16x16x32_bf16(a0[fm], b0v[fn], acc[fm][fn], 0, 0, 0);
                acc[fm][fn] = __builtin_amdgcn_mfma_f32_16x16x32_bf16(a1[fm], b1v[fn], acc[fm][fn], 0, 0, 0);
            }
        __builtin_amdgcn_s_setprio(0);
    }
#undef STAGE

    // ---- epilogue: D mapping col = lane&15, row = (lane>>4)*4 + reg ----
    const int rbase = kq * 4;
    if (MODE == 0) {
#pragma unroll
        for (int fm = 0; fm < 8; ++fm) {
#pragma unroll
            for (int rr = 0; rr < 4; ++rr) {
                const int gm = m0 + wr * 128 + fm * 16 + rbase + rr;
                if (gm < kM) {
                    const float bias = biasC[gm];
#pragma unroll
                    for (int fn = 0; fn < 4; ++fn) {
                        const int gn = n0 + wc * 64 + fn * 16 + fr;
                        qkv[(size_t)gm * kNT + gn] = f2bf(acc[fm][fn][rr] + bias);
                    }
                }
            }
        }
    } else {
        const float g = gamma[0];
        const float* xb = x + (size_t)bz * zso;
        float* ob = out + (size_t)bz * zso;
#pragma unroll
        for (int fm = 0; fm < 8; ++fm)
#pragma unroll
            for (int fn = 0; fn < 4; ++fn)
#pragma unroll
                for (int rr = 0; rr < 4; ++rr) {
                    const size_t idx = (size_t)(m0 + wr*128 + fm*16 + rbase + rr) * kN
                                     + (n0 + wc*64 + fn*16 + fr);
                    ob[idx] = g * acc[fm][fn][rr] + xb[idx];
                }
    }
}

// ---------------- row softmax fp32 -> bf16 ----------------
__global__ __launch_bounds__(256)
void softmax_bf(const float* __restrict__ e, short* __restrict__ attnb)
{
    const int i = blockIdx.x, b = blockIdx.y, tid = threadIdx.x;
    const float* row = e + ((size_t)b * kN + i) * kN;

    float4 vv = *(const float4*)(row + tid * 4);
    float m = fmaxf(fmaxf(vv.x, vv.y), fmaxf(vv.z, vv.w));

    __shared__ float red[8];
#pragma unroll
    for (int off = 32; off > 0; off >>= 1)
        m = fmaxf(m, __shfl_down(m, off));
    if ((tid & 63) == 0) red[tid >> 6] = m;
    __syncthreads();
    m = fmaxf(fmaxf(red[0], red[1]), fmaxf(red[2], red[3]));

    float e0 = expf(vv.x - m), e1 = expf(vv.y - m);
    float e2 = expf(vv.z - m), e3 = expf(vv.w - m);
    float s = e0 + e1 + e2 + e3;
#pragma unroll
    for (int off = 32; off > 0; off >>= 1)
        s += __shfl_down(s, off);
    if ((tid & 63) == 0) red[4 + (tid >> 6)] = s;
    __syncthreads();
    s = red[4] + red[5] + red[6] + red[7];

    const float inv = 1.0f / s;
    s16x4 o;
    o[0] = f2bf(e0 * inv); o[1] = f2bf(e1 * inv);
    o[2] = f2bf(e2 * inv); o[3] = f2bf(e3 * inv);
    *(s16x4*)(attnb + ((size_t)b * kN + i) * kN + tid * 4) = o;
}

extern "C" void kernel_launch(void* const* d_in, const int* in_sizes, int n_in,
                              void* d_out, int out_size, void* d_ws, size_t ws_size,
                              hipStream_t stream) {
    const float* x     = (const float*)d_in[0];
    const float* Wq    = (const float*)d_in[1];
    const float* bq    = (const float*)d_in[2];
    const float* Wk    = (const float*)d_in[3];
    const float* bk    = (const float*)d_in[4];
    const float* Wv    = (const float*)d_in[5];
    const float* bv    = (const float*)d_in[6];
    const float* gamma = (const float*)d_in[7];
    float* out = (float*)d_out;

    char* base = (char*)d_ws;
    short* xbT   = (short*)(base);
    short* attnb = (short*)(base);
    short* qT    = (short*)(base + 16777216);
    short* kT    = (short*)(base + 24641536);
    short* Wc    = (short*)(base + 62914560);
    float* attnf = (float*)(base + 62914560);
    float* biasC = (float*)(base + 100270080);
    short* qkv   = (short*)(base + 100289536);

    convert_wc  <<<9120, 256, 0, stream>>>(Wq, Wk, Wv, Wc);
    convert_bias<<<19, 256, 0, stream>>>(bq, bk, bv, biasC);
    transpose_x <<<dim3(32, 120, 8), 256, 0, stream>>>(x, xbT);

    // proj: (4864 x 3840) * (8192 x 3840)^T -> qkv   [m-fastest grid]
    gemm256<0><<<dim3(19, 32, 1), 512, 0, stream>>>(
        Wc, kC, xbT, kC, kC / 64, 0, 0, 0,
        qkv, biasC, nullptr, nullptr, nullptr);

    transpose_qk<<<dim3(256, 30, 1), 256, 0, stream>>>(qkv, qT, kT);

    // energy: per batch (1024 x 480) * (1024 x 480)^T -> E fp32  [legacy]
    gemm_bt_e<<<dim3(8, 8, 8), 256, 0, stream>>>(
        qT, kC8, kT, kC8, kC8 / 32,
        (long)kN * kC8, (long)kN * kC8, (long)kN * kN, attnf);

    softmax_bf<<<dim3(kN, kB), 256, 0, stream>>>(attnf, attnb);

    // PV: per batch (3840 x 1024) * (1024 x 1024)^T -> out = gamma*acc + x
    gemm256<2><<<dim3(15, 4, 8), 512, 0, stream>>>(
        qkv + (size_t)960 * kNT, kNT, attnb, kN, kN / 64,
        (long)kN, (long)kN * kN, (long)kC * kN,
        nullptr, nullptr, x, gamma, out);
}